// Round 17
// baseline (272.992 us; speedup 1.0000x reference)
//
#include <hip/hip_runtime.h>
#include <hip/hip_fp16.h>
#include <math.h>

// CurvatureGatedGCN: out = L2( relu( L1(x) ) )
// Aggregate-then-GEMM (convs are linear in aggregated features):
//   L(v)[c] = aggG[c] @ Wh + bh + aggS[c] @ Wt + sw[c]*bt
// CSR build: ONE u64 far-atomic per edge (ticket CSR) -- measured floor
// ~49us/1M atomics (sector write-through, ~20G atomics/s).
// R10: gather path compressed to fp16 (v-row = one 128B line) and meta
// packed to 8B {row, norm:f16, ghet:f16} -> agg/fill bytes halved.

#define D 64
#define PSHIFT 45
#define PSCALE 274877906944.0f        // 2^38
#define PMASK  ((1ull << PSHIFT) - 1)

typedef unsigned long long u64;
typedef int iv2 __attribute__((ext_vector_type(2)));   // 8B meta, NT-loadable

__device__ inline float2 h2f2(int bits) {
  __half2 h = __builtin_bit_cast(__half2, bits);
  return __half22float2(h);
}

__global__ void k_phase1(const int* __restrict__ col, const float* __restrict__ curv,
                         u64* __restrict__ packed, float* __restrict__ gbuf,
                         unsigned short* __restrict__ rank, int E) {
  int e = blockIdx.x * blockDim.x + threadIdx.x;
  if (e >= E) return;
  int c = col[e];
  float g = 1.0f / (1.0f + expf(-curv[e] * 0.2f));
  gbuf[e] = g;                                   // cache gate for k_fill
  u64 inc = ((u64)1 << PSHIFT) | (u64)(g * PSCALE);
  u64 old = atomicAdd(&packed[c], inc);          // ONE far-atomic per edge
  rank[e] = (unsigned short)(old >> PSHIFT);     // CSR ticket
}

// x (f32) -> xh (f16), 4 elems/thread
__global__ void k_cvt(const float* __restrict__ x, __half* __restrict__ xh, int n4) {
  int i = blockIdx.x * blockDim.x + threadIdx.x;
  if (i >= n4) return;
  float4 a = ((const float4*)x)[i];
  __half2 lo = __floats2half2_rn(a.x, a.y);
  __half2 hi = __floats2half2_rn(a.z, a.w);
  iv2 pk;
  pk.x = __builtin_bit_cast(int, lo);
  pk.y = __builtin_bit_cast(int, hi);
  ((iv2*)xh)[i] = pk;
}

// ---- 3-phase exclusive scan (n <= 256*256) ----
__global__ void k_scanA(const u64* __restrict__ packed, int* __restrict__ part,
                        int* __restrict__ bsum, int n) {
  __shared__ int tmp[256];
  int tid = threadIdx.x;
  int gid = blockIdx.x * 256 + tid;
  int v = (gid < n) ? (int)(packed[gid] >> PSHIFT) : 0;
  tmp[tid] = v;
  __syncthreads();
  for (int off = 1; off < 256; off <<= 1) {
    int t = (tid >= off) ? tmp[tid - off] : 0;
    __syncthreads();
    tmp[tid] += t;
    __syncthreads();
  }
  if (gid < n) part[gid] = tmp[tid] - v;
  if (tid == 255) bsum[blockIdx.x] = tmp[255];
}

__global__ void k_scanB(int* __restrict__ bsum, int nb) {
  __shared__ int tmp[256];
  int tid = threadIdx.x;
  int v = (tid < nb) ? bsum[tid] : 0;
  tmp[tid] = v;
  __syncthreads();
  for (int off = 1; off < 256; off <<= 1) {
    int t = (tid >= off) ? tmp[tid - off] : 0;
    __syncthreads();
    tmp[tid] += t;
    __syncthreads();
  }
  if (tid < nb) bsum[tid] = tmp[tid] - v;
}

__global__ void k_scanC(const int* __restrict__ part, const int* __restrict__ bsum,
                        const u64* __restrict__ packed,
                        int* __restrict__ ptr, float* __restrict__ dinv,
                        int n, int E) {
  int gid = blockIdx.x * 256 + threadIdx.x;
  if (gid < n) {
    ptr[gid] = part[gid] + bsum[gid >> 8];
    float degw = (float)(packed[gid] & PMASK) * (1.0f / PSCALE);
    dinv[gid] = rsqrtf(1.0f + degw);             // deg = 1 + sum(g)
  }
  if (gid == 0) ptr[n] = E;
}

// Atomic-free CSR fill: pos = ptr[col] + rank. meta = 8B {row, norm:f16, ghet:f16}
__global__ void k_fill(const int* __restrict__ row, const int* __restrict__ col,
                       const float* __restrict__ gbuf,
                       const unsigned short* __restrict__ rank,
                       const int* __restrict__ ptr, const float* __restrict__ dinv,
                       iv2* __restrict__ meta, int E) {
  int e = blockIdx.x * blockDim.x + threadIdx.x;
  if (e >= E) return;
  int c = col[e];
  int r = row[e];
  float g = gbuf[e];
  int pos = ptr[c] + rank[e];
  __half2 ng = __floats2half2_rn(dinv[r] * g * dinv[c], 1.0f - g);
  iv2 m;
  m.x = r;
  m.y = __builtin_bit_cast(int, ng);
  __builtin_nontemporal_store(m, &meta[pos]);
}

// Aggregation: one node per wave, lane = feature (f16 storage, f32 math).
// Per-edge wave traffic: 128B feature row (one cache line) + 8B meta.
__global__ __launch_bounds__(256) void k_agg(
    const __half* __restrict__ v, const int* __restrict__ ptr,
    const iv2* __restrict__ meta, const float* __restrict__ dinv,
    float* __restrict__ aggG, float* __restrict__ aggS,
    float* __restrict__ swv, int n) {
  int wid = __builtin_amdgcn_readfirstlane(threadIdx.x >> 6);
  int lane = threadIdx.x & 63;
  int c = blockIdx.x * 4 + wid;
  if (c >= n) return;

  float vc = __half2float(v[(size_t)c * D + lane]);
  float dc = dinv[c];
  float accG = dc * dc * vc;        // GCN self-loop term
  float accS = 0.0f, sw = 0.0f;
  int s = ptr[c], e = ptr[c + 1];

  int i = s;
#pragma unroll 1
  for (; i + 8 <= e; i += 8) {
    iv2 m[8];
    float vr[8];
#pragma unroll
    for (int u = 0; u < 8; ++u) m[u] = __builtin_nontemporal_load(&meta[i + u]);
#pragma unroll
    for (int u = 0; u < 8; ++u)
      vr[u] = __half2float(v[(size_t)m[u].x * D + lane]);
#pragma unroll
    for (int u = 0; u < 8; ++u) {
      float2 ng = h2f2(m[u].y);
      accG = fmaf(ng.x, vr[u], accG);
      accS = fmaf(ng.y, fabsf(vc - vr[u]), accS);
      sw += ng.y;
    }
  }
  for (; i < e; ++i) {
    iv2 m = __builtin_nontemporal_load(&meta[i]);
    float vr = __half2float(v[(size_t)m.x * D + lane]);
    float2 ng = h2f2(m.y);
    accG = fmaf(ng.x, vr, accG);
    accS = fmaf(ng.y, fabsf(vc - vr), accS);
    sw += ng.y;
  }

  aggG[(size_t)c * D + lane] = accG;
  aggS[(size_t)c * D + lane] = accS;
  if (lane == 0) swv[c] = sw;
}

// Register-blocked LDS GEMM epilogue (64-node x 64-out tile, 4x4 micro-tile).
// If out_h != null: layer-1 mode, store fp16 h. Else store fp32 to out.
#define AP4 17   // A row stride in float4 (68 floats: pad -> 2-way banks max)
#define FMA4(i, j)                                         \
  acc[i][0] = fmaf(a4[i].j, w4j.x, acc[i][0]);             \
  acc[i][1] = fmaf(a4[i].j, w4j.y, acc[i][1]);             \
  acc[i][2] = fmaf(a4[i].j, w4j.z, acc[i][2]);             \
  acc[i][3] = fmaf(a4[i].j, w4j.w, acc[i][3]);

__global__ __launch_bounds__(256) void k_mlp(
    const float* __restrict__ aggG, const float* __restrict__ aggS,
    const float* __restrict__ swv,
    const float* __restrict__ Wh, const float* __restrict__ bh,
    const float* __restrict__ Wt, const float* __restrict__ bt,
    float* __restrict__ out, __half* __restrict__ out_h, int n, int do_relu) {
  __shared__ float As[64 * 68];     // [node][k-half] padded
  __shared__ float Ws[64 * 64];     // [k-half][col]
  int tid = threadIdx.x;
  int tx = tid & 15, ty = tid >> 4;  // tx: 4-col group, ty: 4-node group
  int base = blockIdx.x * 64;

  float acc[4][4] = {{0.f}};
  const float* aggX = aggG;
  const float* Wx = Wh;

  for (int half = 0; half < 2; ++half) {
#pragma unroll
    for (int j = 0; j < 4; ++j) {
      int idx = tid + j * 256;
      ((float4*)Ws)[idx] = ((const float4*)Wx)[idx];
    }
#pragma unroll
    for (int j = 0; j < 4; ++j) {
      int idx = tid + j * 256;           // 0..1023
      int nl = idx >> 4, kk = idx & 15;
      int gn = min(base + nl, n - 1);
      ((float4*)As)[nl * AP4 + kk] = ((const float4*)aggX)[(size_t)gn * 16 + kk];
    }
    __syncthreads();

#pragma unroll
    for (int kk4 = 0; kk4 < 16; ++kk4) {
      float4 a4[4];
#pragma unroll
      for (int i = 0; i < 4; ++i)
        a4[i] = ((const float4*)As)[(4 * ty + i) * AP4 + kk4];
      {
        float4 w4j = ((const float4*)Ws)[(kk4 * 4 + 0) * 16 + tx];
        FMA4(0, x) FMA4(1, x) FMA4(2, x) FMA4(3, x)
      }
      {
        float4 w4j = ((const float4*)Ws)[(kk4 * 4 + 1) * 16 + tx];
        FMA4(0, y) FMA4(1, y) FMA4(2, y) FMA4(3, y)
      }
      {
        float4 w4j = ((const float4*)Ws)[(kk4 * 4 + 2) * 16 + tx];
        FMA4(0, z) FMA4(1, z) FMA4(2, z) FMA4(3, z)
      }
      {
        float4 w4j = ((const float4*)Ws)[(kk4 * 4 + 3) * 16 + tx];
        FMA4(0, w) FMA4(1, w) FMA4(2, w) FMA4(3, w)
      }
    }
    __syncthreads();
    aggX = aggS;
    Wx = Wt;
  }

  float4 bh4 = ((const float4*)bh)[tx];
  float4 bt4 = ((const float4*)bt)[tx];
#pragma unroll
  for (int i = 0; i < 4; ++i) {
    int node = base + 4 * ty + i;
    if (node < n) {
      float s = swv[node];
      float4 r;
      r.x = fmaf(s, bt4.x, acc[i][0] + bh4.x);
      r.y = fmaf(s, bt4.y, acc[i][1] + bh4.y);
      r.z = fmaf(s, bt4.z, acc[i][2] + bh4.z);
      r.w = fmaf(s, bt4.w, acc[i][3] + bh4.w);
      if (do_relu) {
        r.x = fmaxf(r.x, 0.f); r.y = fmaxf(r.y, 0.f);
        r.z = fmaxf(r.z, 0.f); r.w = fmaxf(r.w, 0.f);
      }
      if (out_h) {
        __half2 lo = __floats2half2_rn(r.x, r.y);
        __half2 hi = __floats2half2_rn(r.z, r.w);
        iv2 pk;
        pk.x = __builtin_bit_cast(int, lo);
        pk.y = __builtin_bit_cast(int, hi);
        ((iv2*)out_h)[(size_t)node * 16 + tx] = pk;
      } else {
        ((float4*)out)[(size_t)node * 16 + tx] = r;
      }
    }
  }
}

extern "C" void kernel_launch(void* const* d_in, const int* in_sizes, int n_in,
                              void* d_out, int out_size, void* d_ws, size_t ws_size,
                              hipStream_t stream) {
  const float* x    = (const float*)d_in[0];
  const int*   ei   = (const int*)d_in[1];
  const float* curv = (const float*)d_in[2];
  const float* Wh1  = (const float*)d_in[3];
  const float* bh1  = (const float*)d_in[4];
  const float* Wh2  = (const float*)d_in[5];
  const float* bh2  = (const float*)d_in[6];
  const float* Wt1  = (const float*)d_in[7];
  const float* bt1  = (const float*)d_in[8];
  const float* Wt2  = (const float*)d_in[9];
  const float* bt2  = (const float*)d_in[10];

  int n = in_sizes[0] / D;
  int E = in_sizes[2];
  const int* row = ei;
  const int* col = ei + E;
  float* out = (float*)d_out;

  char* w = (char*)d_ws;
  auto carve = [&](size_t bytes) {
    char* p = w;
    w += (bytes + 255) & ~(size_t)255;
    return (void*)p;
  };
  u64*   packed = (u64*)carve((size_t)n * 8);
  float* dinv   = (float*)carve((size_t)n * 4);
  int*   part   = (int*)carve((size_t)n * 4);
  int*   ptr    = (int*)carve((size_t)(n + 1) * 4);
  int*   bsum   = (int*)carve(256 * 4);
  float* gbuf   = (float*)carve((size_t)E * 4);
  unsigned short* rank = (unsigned short*)carve((size_t)E * 2);
  iv2*   meta   = (iv2*)carve((size_t)E * 8);
  __half* xh    = (__half*)carve((size_t)n * D * 2);
  __half* hh    = (__half*)carve((size_t)n * D * 2);
  float* aggG   = (float*)carve((size_t)n * D * 4);   // reused by both layers
  float* aggS   = (float*)carve((size_t)n * D * 4);
  float* swv    = (float*)carve((size_t)n * 4);

  int nbN = (n + 255) / 256;
  int nbE = (E + 255) / 256;
  int nbA = (n + 3) / 4;        // k_agg: 1 node/wave, 4 waves/block
  int nbM = (n + 63) / 64;      // k_mlp: 64-node tile per block
  int n4  = n * D / 4;

  (void)hipMemsetAsync(packed, 0, (size_t)n * 8, stream);
  k_phase1<<<nbE, 256, 0, stream>>>(col, curv, packed, gbuf, rank, E);
  k_cvt<<<(n4 + 255) / 256, 256, 0, stream>>>(x, xh, n4);
  k_scanA<<<nbN, 256, 0, stream>>>(packed, part, bsum, n);
  k_scanB<<<1, 256, 0, stream>>>(bsum, nbN);
  k_scanC<<<nbN, 256, 0, stream>>>(part, bsum, packed, ptr, dinv, n, E);
  k_fill<<<nbE, 256, 0, stream>>>(row, col, gbuf, rank, ptr, dinv, meta, E);

  // layer 1: xh -> hh (relu, fp16 out)
  k_agg<<<nbA, 256, 0, stream>>>(xh, ptr, meta, dinv, aggG, aggS, swv, n);
  k_mlp<<<nbM, 256, 0, stream>>>(aggG, aggS, swv, Wh1, bh1, Wt1, bt1,
                                 nullptr, hh, n, 1);
  // layer 2: hh -> out (fp32)
  k_agg<<<nbA, 256, 0, stream>>>(hh, ptr, meta, dinv, aggG, aggS, swv, n);
  k_mlp<<<nbM, 256, 0, stream>>>(aggG, aggS, swv, Wh2, bh2, Wt2, bt2,
                                 out, nullptr, n, 0);
}